// Round 6
// baseline (389.813 us; speedup 1.0000x reference)
//
#include <hip/hip_runtime.h>
#include <math.h>

#define HN 1024
#define BB 8
#define NN 1024
#define NHEADS 16
#define DH 64
#define M_ROWS (BB * NN)   // 8192

typedef __attribute__((ext_vector_type(8))) short short8;
typedef __attribute__((ext_vector_type(8))) unsigned short ushort8v;
typedef __attribute__((ext_vector_type(4))) float floatx4;
typedef __attribute__((ext_vector_type(4))) unsigned int uint4v;

__device__ __forceinline__ unsigned short f2bf(float f) {
    unsigned int u = __builtin_bit_cast(unsigned int, f);
    u += 0x7fffu + ((u >> 16) & 1u);   // RNE
    return (unsigned short)(u >> 16);
}

__device__ __forceinline__ unsigned int pack2bf(float a, float b) {
    return (unsigned int)f2bf(a) | ((unsigned int)f2bf(b) << 16);
}

__device__ __forceinline__ void gload16(const unsigned short* g, unsigned short* l) {
    __builtin_amdgcn_global_load_lds(
        (const __attribute__((address_space(1))) void*)g,
        (__attribute__((address_space(3))) void*)l, 16, 0, 0);
}

// ---------------------------------------------------------------------------
// hs fp32 -> bf16 (elementwise)
// ---------------------------------------------------------------------------
__global__ __launch_bounds__(256)
void cvt_hs_k(const float* __restrict__ in, unsigned short* __restrict__ out)
{
    int i = (blockIdx.x * 256 + threadIdx.x) * 4;
    float4 v = *(const float4*)(in + i);
    ushort4 o;
    o.x = f2bf(v.x); o.y = f2bf(v.y); o.z = f2bf(v.z); o.w = f2bf(v.w);
    *(ushort4*)&out[i] = o;
}

// ---------------------------------------------------------------------------
// Weight transpose+convert, 4 weights in one launch (z selects).
// W[k][n] fp32 -> out[n][k] bf16. 32x32 LDS tile.
// ---------------------------------------------------------------------------
__global__ __launch_bounds__(256)
void cvt_wT4_k(const float* __restrict__ W0, const float* __restrict__ W1,
               const float* __restrict__ W2, const float* __restrict__ W3,
               unsigned short* __restrict__ o0, unsigned short* __restrict__ o1,
               unsigned short* __restrict__ o2, unsigned short* __restrict__ o3)
{
    __shared__ float Ls[32][33];
    const int z = blockIdx.z;
    const float* W = z == 0 ? W0 : (z == 1 ? W1 : (z == 2 ? W2 : W3));
    unsigned short* out = z == 0 ? o0 : (z == 1 ? o1 : (z == 2 ? o2 : o3));
    const int t = threadIdx.x;
    const int k0 = blockIdx.x * 32, n0 = blockIdx.y * 32;
    const int r = t >> 3, c4 = (t & 7) * 4;
    float4 v = *(const float4*)(W + (size_t)(k0 + r) * HN + n0 + c4);
    Ls[r][c4 + 0] = v.x; Ls[r][c4 + 1] = v.y;
    Ls[r][c4 + 2] = v.z; Ls[r][c4 + 3] = v.w;
    __syncthreads();
    ushort4 o;
    o.x = f2bf(Ls[c4 + 0][r]); o.y = f2bf(Ls[c4 + 1][r]);
    o.z = f2bf(Ls[c4 + 2][r]); o.w = f2bf(Ls[c4 + 3][r]);
    *(ushort4*)&out[(size_t)(n0 + r) * HN + k0 + c4] = o;
}

// ---------------------------------------------------------------------------
// MFMA GEMM: C[M,N] = A[M,K=1024] @ Bt[N,K]^T, 128x128 tile, BK=32.
// mode 0 (QKV, N=3072): +bias, bf16; Q,K -> [b,h,n,d]; V -> [b,h,d,n].
// mode 1 (out-proj): +bias +resid, fp32 row-major.
// ---------------------------------------------------------------------------
__global__ __launch_bounds__(256)
void mfma_gemm_k(const unsigned short* __restrict__ A,
                 const unsigned short* __restrict__ Bt,
                 const float* __restrict__ b0p, const float* __restrict__ b1p,
                 const float* __restrict__ b2p,
                 const float* __restrict__ resid,
                 unsigned short* __restrict__ Qb, unsigned short* __restrict__ Kb,
                 unsigned short* __restrict__ Vtb, float* __restrict__ Yb,
                 int mode)
{
    __shared__ unsigned short smem[128 * 136];
    unsigned short* As = smem;
    unsigned short* Bs = smem + 4096;

    const int tid  = threadIdx.x;
    const int wave = tid >> 6, lane = tid & 63;
    const int quad = lane >> 4, n16 = lane & 15;
    const int wm = wave >> 1, wn = wave & 1;
    const int row0 = blockIdx.y * 128;
    const int n0   = blockIdx.x * 128;

    floatx4 acc[4][4];
    #pragma unroll
    for (int mi = 0; mi < 4; ++mi)
        #pragma unroll
        for (int ni = 0; ni < 4; ++ni)
            acc[mi][ni] = (floatx4){0.f, 0.f, 0.f, 0.f};

    const unsigned short* ga = A  + (size_t)(row0 + wave * 32 + (lane >> 2)) * 1024 + (lane & 3) * 8;
    const unsigned short* gb = Bt + (size_t)(n0  + wave * 32 + (lane >> 2)) * 1024 + (lane & 3) * 8;

    for (int k0 = 0; k0 < 1024; k0 += 32) {
        gload16(ga,             As + wave * 1024);
        gload16(ga + 16 * 1024, As + wave * 1024 + 512);
        gload16(gb,             Bs + wave * 1024);
        gload16(gb + 16 * 1024, Bs + wave * 1024 + 512);
        ga += 32; gb += 32;
        __syncthreads();

        short8 a[4], b[4];
        #pragma unroll
        for (int mi = 0; mi < 4; ++mi)
            a[mi] = *(const short8*)&As[(wm * 64 + mi * 16 + n16) * 32 + quad * 8];
        #pragma unroll
        for (int ni = 0; ni < 4; ++ni)
            b[ni] = *(const short8*)&Bs[(wn * 64 + ni * 16 + n16) * 32 + quad * 8];
        #pragma unroll
        for (int mi = 0; mi < 4; ++mi)
            #pragma unroll
            for (int ni = 0; ni < 4; ++ni)
                acc[mi][ni] = __builtin_amdgcn_mfma_f32_16x16x32_bf16(
                    a[mi], b[ni], acc[mi][ni], 0, 0, 0);
        __syncthreads();
    }

    if (mode == 0) {
        const int sel = n0 >> 10;
        const int c0  = n0 & 1023;
        const float* bias = sel == 0 ? b0p : (sel == 1 ? b1p : b2p);
        float bvv[4];
        #pragma unroll
        for (int ni = 0; ni < 4; ++ni)
            bvv[ni] = bias[c0 + wn * 64 + ni * 16 + n16];

        #pragma unroll
        for (int mi = 0; mi < 4; ++mi)
            #pragma unroll
            for (int ni = 0; ni < 4; ++ni)
                #pragma unroll
                for (int r = 0; r < 4; ++r)
                    smem[(wm * 64 + mi * 16 + quad * 4 + r) * 136 +
                         wn * 64 + ni * 16 + n16] = f2bf(acc[mi][ni][r] + bvv[ni]);
        __syncthreads();

        if (sel < 2) {   // Q, K: [b,h,n,d]
            unsigned short* outb = sel == 0 ? Qb : Kb;
            #pragma unroll
            for (int i = 0; i < 8; ++i) {
                int c = i * 256 + tid;
                int r = c >> 4;
                int colc = (c & 15) * 8;
                ushort8v v = *(const ushort8v*)&smem[r * 136 + colc];
                int row = row0 + r, bb = row >> 10, nn = row & 1023;
                int gc = c0 + colc, head = gc >> 6, d = gc & 63;
                *(ushort8v*)&outb[(((size_t)bb * NHEADS + head) * NN + nn) * DH + d] = v;
            }
        } else {         // V: [b,h,d,n]
            #pragma unroll
            for (int i = 0; i < 8; ++i) {
                int c = i * 256 + tid;
                int dcol = c >> 4;
                int nnc = (c & 15) * 8;
                ushort8v v;
                #pragma unroll
                for (int j = 0; j < 8; ++j)
                    v[j] = smem[(nnc + j) * 136 + dcol];
                int gc = c0 + dcol, head = gc >> 6, d = gc & 63;
                int row = row0 + nnc, bb = row >> 10, nn = row & 1023;
                *(ushort8v*)&Vtb[(((size_t)bb * NHEADS + head) * DH + d) * NN + nn] = v;
            }
        }
    } else {
        float bvv[4];
        #pragma unroll
        for (int ni = 0; ni < 4; ++ni)
            bvv[ni] = b0p[n0 + wn * 64 + ni * 16 + n16];
        #pragma unroll
        for (int mi = 0; mi < 4; ++mi)
            #pragma unroll
            for (int r = 0; r < 4; ++r) {
                int row = row0 + wm * 64 + mi * 16 + quad * 4 + r;
                const float* rr = resid + (size_t)row * HN;
                float* yr = Yb + (size_t)row * HN;
                #pragma unroll
                for (int ni = 0; ni < 4; ++ni) {
                    int col = n0 + wn * 64 + ni * 16 + n16;
                    yr[col] = acc[mi][ni][r] + bvv[ni] + rr[col];
                }
            }
    }
}

// ---------------------------------------------------------------------------
// MFMA flash attention v3: S^T formulation + key-row-permuted K staging so
// the S^T output registers ARE the PV B-operand (P never touches LDS),
// 32 q-rows per wave (128 q/block), XOR-swizzled LDS, async double-buffer.
//
// Key permutation: LDS K row l holds global key
//   g(l) = (l>>5)*32 + ((l>>2)&3)*8 + ((l>>4)&1)*4 + (l&3)
// so lane (quad,n16)'s C-layout rows of S^T subtiles {2c,2c+1} are exactly
// keys c*32 + quad*8 + {0..7} == the B-frag for PV group c. V stays natural.
// ---------------------------------------------------------------------------
__global__ __launch_bounds__(256)
void attn_mfma_k(const unsigned short* __restrict__ Q,
                 const unsigned short* __restrict__ K,
                 const unsigned short* __restrict__ Vt,
                 const int* __restrict__ mask,
                 unsigned short* __restrict__ ctx)
{
    __shared__ unsigned short KsB[2 * 4096];   // [buf][row 64][d 64] swizzled, permuted keys
    __shared__ unsigned short VsB[2 * 4096];   // [buf][d 64][key 64] swizzled, natural

    const int tid  = threadIdx.x;
    const int wave = tid >> 6, lane = tid & 63;
    const int quad = lane >> 4, n16 = lane & 15;
    const int sw   = n16 & 7;
    const int q0 = blockIdx.x << 7;            // 128 q per block
    const int h  = blockIdx.y, b = blockIdx.z;
    const int bh = b * NHEADS + h;
    const int qw = q0 + wave * 32;             // wave covers q rows qw..qw+31
    const float SC = 0.125f * 1.44269504088896340736f;  // scale * log2(e)

    // Q fragments (B-operand of S^T) for both q-halves
    short8 aq[2][2];
    #pragma unroll
    for (int qh = 0; qh < 2; ++qh) {
        const unsigned short* qp = Q + ((size_t)bh * NN + qw + qh * 16 + n16) * DH;
        aq[qh][0] = *(const short8*)(qp + quad * 8);
        aq[qh][1] = *(const short8*)(qp + 32 + quad * 8);
    }

    floatx4 O[2][4];
    #pragma unroll
    for (int qh = 0; qh < 2; ++qh)
        #pragma unroll
        for (int d4 = 0; d4 < 4; ++d4)
            O[qh][d4] = (floatx4){0.f, 0.f, 0.f, 0.f};
    float lsum[2] = {0.f, 0.f};

    const unsigned short* Kg = K  + (size_t)bh * NN * DH;
    const unsigned short* Vg = Vt + (size_t)bh * DH * NN;

    // Staging: wave w fills LDS rows [16w,16w+16), 2 issues of 1 KB.
    // lane l -> LDS row l0 = 16w + (l>>3), phys chunk l&7; source chunk is
    // un-swizzled (l&7)^(r8&7); K source row is the permuted key g(l0).
    const int r8 = lane >> 3;
    const int cs = (lane & 7) ^ (r8 & 7);
    const int gk0 = ((wave >> 1) << 5) + ((r8 >> 2) << 3) + ((wave & 1) << 2) + (r8 & 3);
    const unsigned short* kg0 = Kg + (size_t)gk0 * DH + cs * 8;
    const unsigned short* kg1 = kg0 + 16 * DH;             // g(l0+8) = g(l0)+16
    const unsigned short* vg0 = Vg + (size_t)(wave * 16 + r8) * NN + cs * 8;
    const unsigned short* vg1 = vg0 + 8 * NN;
    unsigned short* lk = KsB + wave * 1024;
    unsigned short* lv = VsB + wave * 1024;

    // mask base per q-half; per-(kt) offset = (kt>>1)*32 + quad*8 + (kt&1)*4
    const int* mp0 = mask + ((size_t)b * NN + qw + n16) * NN + quad * 8;
    const int* mp1 = mp0 + 16 * NN;

    // prologue: tile 0 -> buffer 0
    gload16(kg0, lk);  gload16(kg1, lk + 512);
    gload16(vg0, lv);  gload16(vg1, lv + 512);

    for (int t = 0; t < 16; ++t) {
        __syncthreads();                       // implicit vmcnt(0): tile t resident
        const int cur = t & 1;
        if (t < 15) {
            const int nxt = cur ^ 1;
            kg0 += 4096; kg1 += 4096; vg0 += 64; vg1 += 64;
            gload16(kg0, lk + nxt * 4096); gload16(kg1, lk + nxt * 4096 + 512);
            gload16(vg0, lv + nxt * 4096); gload16(vg1, lv + nxt * 4096 + 512);
        }
        const unsigned short* Kc = KsB + cur * 4096;
        const unsigned short* Vc = VsB + cur * 4096;
        const int kbase = t * 64;

        // S^T pass: per kt, K-frag read once, used by both q-halves.
        // pk[qh][kt*2+half]: packed bf16 P values (B-frag for PV, in regs).
        unsigned int pk[2][8];
        #pragma unroll
        for (int kt = 0; kt < 4; ++kt) {
            const unsigned short* kr = Kc + (kt * 16 + n16) * 64;
            short8 kf0 = *(const short8*)&kr[(quad ^ sw) * 8];
            short8 kf1 = *(const short8*)&kr[((quad + 4) ^ sw) * 8];
            const int moff = kbase + ((kt >> 1) << 5) + ((kt & 1) << 2);
            #pragma unroll
            for (int qh = 0; qh < 2; ++qh) {
                floatx4 s = (floatx4){0.f, 0.f, 0.f, 0.f};
                s = __builtin_amdgcn_mfma_f32_16x16x32_bf16(kf0, aq[qh][0], s, 0, 0, 0);
                s = __builtin_amdgcn_mfma_f32_16x16x32_bf16(kf1, aq[qh][1], s, 0, 0, 0);
                int4 m4 = *(const int4*)((qh ? mp1 : mp0) + moff);
                float p0 = m4.x ? exp2f(s[0] * SC) : 0.f;
                float p1 = m4.y ? exp2f(s[1] * SC) : 0.f;
                float p2 = m4.z ? exp2f(s[2] * SC) : 0.f;
                float p3 = m4.w ? exp2f(s[3] * SC) : 0.f;
                lsum[qh] += (p0 + p1) + (p2 + p3);
                pk[qh][kt * 2]     = pack2bf(p0, p1);
                pk[qh][kt * 2 + 1] = pack2bf(p2, p3);
            }
        }

        // PV pass: O^T += V^T P^T. A = V-frag from LDS (shared by q-halves),
        // B = pk registers. Group c covers keys c*32..c*32+31.
        #pragma unroll
        for (int c = 0; c < 2; ++c) {
            short8 vb[4];
            #pragma unroll
            for (int d4 = 0; d4 < 4; ++d4)
                vb[d4] = *(const short8*)&Vc[(d4 * 16 + n16) * 64 +
                                             ((4 * c + quad) ^ sw) * 8];
            #pragma unroll
            for (int qh = 0; qh < 2; ++qh) {
                uint4v u = {pk[qh][c * 4], pk[qh][c * 4 + 1],
                            pk[qh][c * 4 + 2], pk[qh][c * 4 + 3]};
                short8 pb = __builtin_bit_cast(short8, u);
                #pragma unroll
                for (int d4 = 0; d4 < 4; ++d4)
                    O[qh][d4] = __builtin_amdgcn_mfma_f32_16x16x32_bf16(
                        vb[d4], pb, O[qh][d4], 0, 0, 0);
            }
        }
    }

    // Epilogue: per-lane row sums (lane covers 1/4 of keys for q = n16);
    // sum over the 4 quads, then write O^T (rows d, col q=n16) as bf16.
    #pragma unroll
    for (int qh = 0; qh < 2; ++qh) {
        float ltot = lsum[qh];
        ltot += __shfl_xor(ltot, 16);
        ltot += __shfl_xor(ltot, 32);
        const float inv = 1.0f / ltot;
        unsigned short* cp = ctx + ((size_t)b * NN + qw + qh * 16 + n16) * HN
                             + h * DH + quad * 4;
        #pragma unroll
        for (int d4 = 0; d4 < 4; ++d4) {
            unsigned int u01 = pack2bf(O[qh][d4][0] * inv, O[qh][d4][1] * inv);
            unsigned int u23 = pack2bf(O[qh][d4][2] * inv, O[qh][d4][3] * inv);
            *(uint2*)(cp + d4 * 16) = (uint2){u01, u23};
        }
    }
}

// ---------------------------------------------------------------------------
// LayerNorm per row (eps = 1e-12) + fused state-row extraction.
// ---------------------------------------------------------------------------
__global__ __launch_bounds__(256)
void ln_ext_k(const float* __restrict__ y, const float* __restrict__ gamma,
              const float* __restrict__ beta, const int* __restrict__ conv_len,
              float* __restrict__ out, float* __restrict__ he, float* __restrict__ pt)
{
    const int row = blockIdx.x;
    const int t = threadIdx.x;
    float4 v = ((const float4*)(y + (size_t)row * HN))[t];
    float s  = v.x + v.y + v.z + v.w;
    float s2 = v.x * v.x + v.y * v.y + v.z * v.z + v.w * v.w;
    #pragma unroll
    for (int off = 32; off > 0; off >>= 1) {
        s  += __shfl_down(s, off);
        s2 += __shfl_down(s2, off);
    }
    __shared__ float ws1[4], ws2[4];
    __shared__ float smu, sinv;
    if ((t & 63) == 0) { ws1[t >> 6] = s; ws2[t >> 6] = s2; }
    __syncthreads();
    if (t == 0) {
        float ts  = ws1[0] + ws1[1] + ws1[2] + ws1[3];
        float ts2 = ws2[0] + ws2[1] + ws2[2] + ws2[3];
        float mu  = ts * (1.0f / 1024.0f);
        float var = ts2 * (1.0f / 1024.0f) - mu * mu;
        smu  = mu;
        sinv = 1.0f / sqrtf(var + 1e-12f);
    }
    __syncthreads();
    const float mu = smu, inv = sinv;
    float4 g = ((const float4*)gamma)[t];
    float4 be = ((const float4*)beta)[t];
    float4 o;
    o.x = (v.x - mu) * inv * g.x + be.x;
    o.y = (v.y - mu) * inv * g.y + be.y;
    o.z = (v.z - mu) * inv * g.z + be.z;
    o.w = (v.w - mu) * inv * g.w + be.w;
    ((float4*)(out + (size_t)row * HN))[t] = o;

    const int b = row >> 10, n = row & 1023;
    const int base = 6 * conv_len[b];
    if (n == base + 3) ((float4*)(he + (size_t)b * HN))[t] = o;
    if (n == base + 2) ((float4*)(pt + (size_t)b * HN))[t] = o;
}

extern "C" void kernel_launch(void* const* d_in, const int* in_sizes, int n_in,
                              void* d_out, int out_size, void* d_ws, size_t ws_size,
                              hipStream_t stream)
{
    const float* hs    = (const float*)d_in[0];
    const int*   mask  = (const int*)d_in[1];
    const int*   clen  = (const int*)d_in[2];
    const float* Wq    = (const float*)d_in[3];
    const float* bq    = (const float*)d_in[4];
    const float* Wk    = (const float*)d_in[5];
    const float* bk    = (const float*)d_in[6];
    const float* Wv    = (const float*)d_in[7];
    const float* bv    = (const float*)d_in[8];
    const float* Wo    = (const float*)d_in[9];
    const float* bo    = (const float*)d_in[10];
    const float* gamma = (const float*)d_in[11];
    const float* beta  = (const float*)d_in[12];
    float* out = (float*)d_out;

    // ws: Ab 16M | Wt3 6M | Wot 2M | Qb 16M | Kb 16M | Vtb 16M | Ctx 16M = 88 MB
    // Yb (fp32, 32M) aliases Qb+Kb (dead after attention).
    unsigned short* Ab  = (unsigned short*)d_ws;
    unsigned short* Wt3 = Ab  + (size_t)M_ROWS * HN;
    unsigned short* Wot = Wt3 + (size_t)3 * HN * HN;
    unsigned short* Qb  = Wot + (size_t)HN * HN;
    unsigned short* Kb  = Qb  + (size_t)M_ROWS * HN;
    unsigned short* Vtb = Kb  + (size_t)M_ROWS * HN;
    unsigned short* Ctx = Vtb + (size_t)M_ROWS * HN;
    float*          Yb  = (float*)Qb;

    dim3 gb(256);

    hipLaunchKernelGGL(cvt_hs_k, dim3((size_t)M_ROWS * HN / 1024), gb, 0, stream, hs, Ab);
    hipLaunchKernelGGL(cvt_wT4_k, dim3(32, 32, 4), gb, 0, stream,
                       Wq, Wk, Wv, Wo,
                       Wt3, Wt3 + (size_t)HN * HN, Wt3 + (size_t)2 * HN * HN, Wot);

    hipLaunchKernelGGL(mfma_gemm_k, dim3(24, 64), gb, 0, stream,
                       Ab, Wt3, bq, bk, bv, (const float*)nullptr,
                       Qb, Kb, Vtb, (float*)nullptr, 0);

    hipLaunchKernelGGL(attn_mfma_k, dim3(NN / 128, NHEADS, BB), gb, 0, stream,
                       Qb, Kb, Vtb, mask, Ctx);

    hipLaunchKernelGGL(mfma_gemm_k, dim3(8, 64), gb, 0, stream,
                       Ctx, Wot, bo, (const float*)nullptr, (const float*)nullptr, hs,
                       (unsigned short*)nullptr, (unsigned short*)nullptr,
                       (unsigned short*)nullptr, Yb, 1);

    float* he = out + (size_t)BB * NN * HN;
    float* pt = he + BB * HN;
    hipLaunchKernelGGL(ln_ext_k, dim3(M_ROWS), gb, 0, stream, Yb, gamma, beta, clen,
                       out, he, pt);
}

// Round 7
// 359.789 us; speedup vs baseline: 1.0834x; 1.0834x over previous
//
#include <hip/hip_runtime.h>
#include <math.h>

#define HN 1024
#define BB 8
#define NN 1024
#define NHEADS 16
#define DH 64
#define M_ROWS (BB * NN)   // 8192

typedef __attribute__((ext_vector_type(8))) short short8;
typedef __attribute__((ext_vector_type(8))) unsigned short ushort8v;
typedef __attribute__((ext_vector_type(4))) float floatx4;
typedef __attribute__((ext_vector_type(4))) unsigned int uint4v;

__device__ __forceinline__ unsigned short f2bf(float f) {
    unsigned int u = __builtin_bit_cast(unsigned int, f);
    u += 0x7fffu + ((u >> 16) & 1u);   // RNE
    return (unsigned short)(u >> 16);
}

__device__ __forceinline__ unsigned int pack2bf(float a, float b) {
    return (unsigned int)f2bf(a) | ((unsigned int)f2bf(b) << 16);
}

__device__ __forceinline__ void gload16(const unsigned short* g, unsigned short* l) {
    __builtin_amdgcn_global_load_lds(
        (const __attribute__((address_space(1))) void*)g,
        (__attribute__((address_space(3))) void*)l, 16, 0, 0);
}

// ---------------------------------------------------------------------------
// hs fp32 -> bf16 (elementwise)
// ---------------------------------------------------------------------------
__global__ __launch_bounds__(256)
void cvt_hs_k(const float* __restrict__ in, unsigned short* __restrict__ out)
{
    int i = (blockIdx.x * 256 + threadIdx.x) * 4;
    float4 v = *(const float4*)(in + i);
    ushort4 o;
    o.x = f2bf(v.x); o.y = f2bf(v.y); o.z = f2bf(v.z); o.w = f2bf(v.w);
    *(ushort4*)&out[i] = o;
}

// ---------------------------------------------------------------------------
// Weight transpose+convert, 4 weights in one launch (z selects).
// W[k][n] fp32 -> out[n][k] bf16. 32x32 LDS tile.
// ---------------------------------------------------------------------------
__global__ __launch_bounds__(256)
void cvt_wT4_k(const float* __restrict__ W0, const float* __restrict__ W1,
               const float* __restrict__ W2, const float* __restrict__ W3,
               unsigned short* __restrict__ o0, unsigned short* __restrict__ o1,
               unsigned short* __restrict__ o2, unsigned short* __restrict__ o3)
{
    __shared__ float Ls[32][33];
    const int z = blockIdx.z;
    const float* W = z == 0 ? W0 : (z == 1 ? W1 : (z == 2 ? W2 : W3));
    unsigned short* out = z == 0 ? o0 : (z == 1 ? o1 : (z == 2 ? o2 : o3));
    const int t = threadIdx.x;
    const int k0 = blockIdx.x * 32, n0 = blockIdx.y * 32;
    const int r = t >> 3, c4 = (t & 7) * 4;
    float4 v = *(const float4*)(W + (size_t)(k0 + r) * HN + n0 + c4);
    Ls[r][c4 + 0] = v.x; Ls[r][c4 + 1] = v.y;
    Ls[r][c4 + 2] = v.z; Ls[r][c4 + 3] = v.w;
    __syncthreads();
    ushort4 o;
    o.x = f2bf(Ls[c4 + 0][r]); o.y = f2bf(Ls[c4 + 1][r]);
    o.z = f2bf(Ls[c4 + 2][r]); o.w = f2bf(Ls[c4 + 3][r]);
    *(ushort4*)&out[(size_t)(n0 + r) * HN + k0 + c4] = o;
}

// ---------------------------------------------------------------------------
// MFMA GEMM: C[M,N] = A[M,K=1024] @ Bt[N,K]^T, 128x128 tile, BK=32.
// Grid: (row-band, col-band) with ROW in x (fast dim) -> co-XCD blocks share
// the A row-tile in L2.
// mode 0 (QKV, N=3072): +bias, bf16; Q,K -> [b,h,n,d]; V -> [b,h,d,n].
// mode 1 (out-proj): +bias +resid, fp32 row-major.
// ---------------------------------------------------------------------------
__global__ __launch_bounds__(256)
void mfma_gemm_k(const unsigned short* __restrict__ A,
                 const unsigned short* __restrict__ Bt,
                 const float* __restrict__ b0p, const float* __restrict__ b1p,
                 const float* __restrict__ b2p,
                 const float* __restrict__ resid,
                 unsigned short* __restrict__ Qb, unsigned short* __restrict__ Kb,
                 unsigned short* __restrict__ Vtb, float* __restrict__ Yb,
                 int mode)
{
    __shared__ unsigned short smem[128 * 136];
    unsigned short* As = smem;
    unsigned short* Bs = smem + 4096;

    const int tid  = threadIdx.x;
    const int wave = tid >> 6, lane = tid & 63;
    const int quad = lane >> 4, n16 = lane & 15;
    const int wm = wave >> 1, wn = wave & 1;
    const int row0 = blockIdx.x * 128;    // row-band in x: XCD = row%8
    const int n0   = blockIdx.y * 128;

    floatx4 acc[4][4];
    #pragma unroll
    for (int mi = 0; mi < 4; ++mi)
        #pragma unroll
        for (int ni = 0; ni < 4; ++ni)
            acc[mi][ni] = (floatx4){0.f, 0.f, 0.f, 0.f};

    const unsigned short* ga = A  + (size_t)(row0 + wave * 32 + (lane >> 2)) * 1024 + (lane & 3) * 8;
    const unsigned short* gb = Bt + (size_t)(n0  + wave * 32 + (lane >> 2)) * 1024 + (lane & 3) * 8;

    for (int k0 = 0; k0 < 1024; k0 += 32) {
        gload16(ga,             As + wave * 1024);
        gload16(ga + 16 * 1024, As + wave * 1024 + 512);
        gload16(gb,             Bs + wave * 1024);
        gload16(gb + 16 * 1024, Bs + wave * 1024 + 512);
        ga += 32; gb += 32;
        __syncthreads();

        short8 a[4], b[4];
        #pragma unroll
        for (int mi = 0; mi < 4; ++mi)
            a[mi] = *(const short8*)&As[(wm * 64 + mi * 16 + n16) * 32 + quad * 8];
        #pragma unroll
        for (int ni = 0; ni < 4; ++ni)
            b[ni] = *(const short8*)&Bs[(wn * 64 + ni * 16 + n16) * 32 + quad * 8];
        #pragma unroll
        for (int mi = 0; mi < 4; ++mi)
            #pragma unroll
            for (int ni = 0; ni < 4; ++ni)
                acc[mi][ni] = __builtin_amdgcn_mfma_f32_16x16x32_bf16(
                    a[mi], b[ni], acc[mi][ni], 0, 0, 0);
        __syncthreads();
    }

    if (mode == 0) {
        const int sel = n0 >> 10;
        const int c0  = n0 & 1023;
        const float* bias = sel == 0 ? b0p : (sel == 1 ? b1p : b2p);
        float bvv[4];
        #pragma unroll
        for (int ni = 0; ni < 4; ++ni)
            bvv[ni] = bias[c0 + wn * 64 + ni * 16 + n16];

        #pragma unroll
        for (int mi = 0; mi < 4; ++mi)
            #pragma unroll
            for (int ni = 0; ni < 4; ++ni)
                #pragma unroll
                for (int r = 0; r < 4; ++r)
                    smem[(wm * 64 + mi * 16 + quad * 4 + r) * 136 +
                         wn * 64 + ni * 16 + n16] = f2bf(acc[mi][ni][r] + bvv[ni]);
        __syncthreads();

        if (sel < 2) {   // Q, K: [b,h,n,d]
            unsigned short* outb = sel == 0 ? Qb : Kb;
            #pragma unroll
            for (int i = 0; i < 8; ++i) {
                int c = i * 256 + tid;
                int r = c >> 4;
                int colc = (c & 15) * 8;
                ushort8v v = *(const ushort8v*)&smem[r * 136 + colc];
                int row = row0 + r, bb = row >> 10, nn = row & 1023;
                int gc = c0 + colc, head = gc >> 6, d = gc & 63;
                *(ushort8v*)&outb[(((size_t)bb * NHEADS + head) * NN + nn) * DH + d] = v;
            }
        } else {         // V: [b,h,d,n]
            #pragma unroll
            for (int i = 0; i < 8; ++i) {
                int c = i * 256 + tid;
                int dcol = c >> 4;
                int nnc = (c & 15) * 8;
                ushort8v v;
                #pragma unroll
                for (int j = 0; j < 8; ++j)
                    v[j] = smem[(nnc + j) * 136 + dcol];
                int gc = c0 + dcol, head = gc >> 6, d = gc & 63;
                int row = row0 + nnc, bb = row >> 10, nn = row & 1023;
                *(ushort8v*)&Vtb[(((size_t)bb * NHEADS + head) * DH + d) * NN + nn] = v;
            }
        }
    } else {
        float bvv[4];
        #pragma unroll
        for (int ni = 0; ni < 4; ++ni)
            bvv[ni] = b0p[n0 + wn * 64 + ni * 16 + n16];
        #pragma unroll
        for (int mi = 0; mi < 4; ++mi)
            #pragma unroll
            for (int r = 0; r < 4; ++r) {
                int row = row0 + wm * 64 + mi * 16 + quad * 4 + r;
                const float* rr = resid + (size_t)row * HN;
                float* yr = Yb + (size_t)row * HN;
                #pragma unroll
                for (int ni = 0; ni < 4; ++ni) {
                    int col = n0 + wn * 64 + ni * 16 + n16;
                    yr[col] = acc[mi][ni][r] + bvv[ni] + rr[col];
                }
            }
    }
}

// ---------------------------------------------------------------------------
// MFMA flash attention v4: register-P (key-permuted K staging), 32 q/wave,
// XOR-swizzled LDS, async dbuf, XCD-locality grid (blockIdx.x = batch:
// linear%8 == b, so each XCD runs exactly one batch -> mask/K/V L2-resident
// with 16-head / 8-qtile concurrent reuse). Mask loads hoisted to tile top;
// native __expf.
// ---------------------------------------------------------------------------
__global__ __launch_bounds__(256)
void attn_mfma_k(const unsigned short* __restrict__ Q,
                 const unsigned short* __restrict__ K,
                 const unsigned short* __restrict__ Vt,
                 const int* __restrict__ mask,
                 unsigned short* __restrict__ ctx)
{
    __shared__ unsigned short KsB[2 * 4096];   // [buf][row 64][d 64] swizzled, permuted keys
    __shared__ unsigned short VsB[2 * 4096];   // [buf][d 64][key 64] swizzled, natural

    const int tid  = threadIdx.x;
    const int wave = tid >> 6, lane = tid & 63;
    const int quad = lane >> 4, n16 = lane & 15;
    const int sw   = n16 & 7;
    const int b  = blockIdx.x;                 // batch in x: XCD = b
    const int q0 = blockIdx.y << 7;            // 128 q per block
    const int h  = blockIdx.z;
    const int bh = b * NHEADS + h;
    const int qw = q0 + wave * 32;             // wave covers q rows qw..qw+31

    // Q fragments (B-operand of S^T) for both q-halves
    short8 aq[2][2];
    #pragma unroll
    for (int qh = 0; qh < 2; ++qh) {
        const unsigned short* qp = Q + ((size_t)bh * NN + qw + qh * 16 + n16) * DH;
        aq[qh][0] = *(const short8*)(qp + quad * 8);
        aq[qh][1] = *(const short8*)(qp + 32 + quad * 8);
    }

    floatx4 O[2][4];
    #pragma unroll
    for (int qh = 0; qh < 2; ++qh)
        #pragma unroll
        for (int d4 = 0; d4 < 4; ++d4)
            O[qh][d4] = (floatx4){0.f, 0.f, 0.f, 0.f};
    float lsum[2] = {0.f, 0.f};

    const unsigned short* Kg = K  + (size_t)bh * NN * DH;
    const unsigned short* Vg = Vt + (size_t)bh * DH * NN;

    // Staging: wave w fills LDS rows [16w,16w+16), 2 issues of 1 KB.
    const int r8 = lane >> 3;
    const int cs = (lane & 7) ^ (r8 & 7);
    const int gk0 = ((wave >> 1) << 5) + ((r8 >> 2) << 3) + ((wave & 1) << 2) + (r8 & 3);
    const unsigned short* kg0 = Kg + (size_t)gk0 * DH + cs * 8;
    const unsigned short* kg1 = kg0 + 16 * DH;             // g(l0+8) = g(l0)+16
    const unsigned short* vg0 = Vg + (size_t)(wave * 16 + r8) * NN + cs * 8;
    const unsigned short* vg1 = vg0 + 8 * NN;
    unsigned short* lk = KsB + wave * 1024;
    unsigned short* lv = VsB + wave * 1024;

    // mask base per q-half; per-(kt) offset = (kt>>1)*32 + quad*8 + (kt&1)*4
    const int* mp0 = mask + ((size_t)b * NN + qw + n16) * NN + quad * 8;
    const int* mp1 = mp0 + 16 * NN;

    // prologue: tile 0 -> buffer 0
    gload16(kg0, lk);  gload16(kg1, lk + 512);
    gload16(vg0, lv);  gload16(vg1, lv + 512);

    for (int t = 0; t < 16; ++t) {
        __syncthreads();                       // implicit vmcnt(0): tile t resident
        const int cur = t & 1;
        if (t < 15) {
            const int nxt = cur ^ 1;
            kg0 += 4096; kg1 += 4096; vg0 += 64; vg1 += 64;
            gload16(kg0, lk + nxt * 4096); gload16(kg1, lk + nxt * 4096 + 512);
            gload16(vg0, lv + nxt * 4096); gload16(vg1, lv + nxt * 4096 + 512);
        }
        const unsigned short* Kc = KsB + cur * 4096;
        const unsigned short* Vc = VsB + cur * 4096;
        const int kbase = t * 64;

        // hoist the tile's 8 mask int4 loads: full S phase to cover latency
        int4 m4a[2][4];
        #pragma unroll
        for (int kt = 0; kt < 4; ++kt) {
            const int moff = kbase + ((kt >> 1) << 5) + ((kt & 1) << 2);
            m4a[0][kt] = *(const int4*)(mp0 + moff);
            m4a[1][kt] = *(const int4*)(mp1 + moff);
        }

        // S^T pass: per kt, K-frag read once, used by both q-halves.
        unsigned int pk[2][8];
        #pragma unroll
        for (int kt = 0; kt < 4; ++kt) {
            const unsigned short* kr = Kc + (kt * 16 + n16) * 64;
            short8 kf0 = *(const short8*)&kr[(quad ^ sw) * 8];
            short8 kf1 = *(const short8*)&kr[((quad + 4) ^ sw) * 8];
            #pragma unroll
            for (int qh = 0; qh < 2; ++qh) {
                floatx4 s = (floatx4){0.f, 0.f, 0.f, 0.f};
                s = __builtin_amdgcn_mfma_f32_16x16x32_bf16(kf0, aq[qh][0], s, 0, 0, 0);
                s = __builtin_amdgcn_mfma_f32_16x16x32_bf16(kf1, aq[qh][1], s, 0, 0, 0);
                int4 m4 = m4a[qh][kt];
                float p0 = m4.x ? __expf(s[0] * 0.125f) : 0.f;
                float p1 = m4.y ? __expf(s[1] * 0.125f) : 0.f;
                float p2 = m4.z ? __expf(s[2] * 0.125f) : 0.f;
                float p3 = m4.w ? __expf(s[3] * 0.125f) : 0.f;
                lsum[qh] += (p0 + p1) + (p2 + p3);
                pk[qh][kt * 2]     = pack2bf(p0, p1);
                pk[qh][kt * 2 + 1] = pack2bf(p2, p3);
            }
        }

        // PV pass: O^T += V^T P^T. A = V-frag from LDS, B = pk registers.
        #pragma unroll
        for (int c = 0; c < 2; ++c) {
            short8 vb[4];
            #pragma unroll
            for (int d4 = 0; d4 < 4; ++d4)
                vb[d4] = *(const short8*)&Vc[(d4 * 16 + n16) * 64 +
                                             ((4 * c + quad) ^ sw) * 8];
            #pragma unroll
            for (int qh = 0; qh < 2; ++qh) {
                uint4v u = {pk[qh][c * 4], pk[qh][c * 4 + 1],
                            pk[qh][c * 4 + 2], pk[qh][c * 4 + 3]};
                short8 pb = __builtin_bit_cast(short8, u);
                #pragma unroll
                for (int d4 = 0; d4 < 4; ++d4)
                    O[qh][d4] = __builtin_amdgcn_mfma_f32_16x16x32_bf16(
                        vb[d4], pb, O[qh][d4], 0, 0, 0);
            }
        }
    }

    // Epilogue: per-lane row sums; sum over the 4 quads, write O^T as bf16.
    #pragma unroll
    for (int qh = 0; qh < 2; ++qh) {
        float ltot = lsum[qh];
        ltot += __shfl_xor(ltot, 16);
        ltot += __shfl_xor(ltot, 32);
        const float inv = 1.0f / ltot;
        unsigned short* cp = ctx + ((size_t)b * NN + qw + qh * 16 + n16) * HN
                             + h * DH + quad * 4;
        #pragma unroll
        for (int d4 = 0; d4 < 4; ++d4) {
            unsigned int u01 = pack2bf(O[qh][d4][0] * inv, O[qh][d4][1] * inv);
            unsigned int u23 = pack2bf(O[qh][d4][2] * inv, O[qh][d4][3] * inv);
            *(uint2*)(cp + d4 * 16) = (uint2){u01, u23};
        }
    }
}

// ---------------------------------------------------------------------------
// LayerNorm per row (eps = 1e-12) + fused state-row extraction.
// ---------------------------------------------------------------------------
__global__ __launch_bounds__(256)
void ln_ext_k(const float* __restrict__ y, const float* __restrict__ gamma,
              const float* __restrict__ beta, const int* __restrict__ conv_len,
              float* __restrict__ out, float* __restrict__ he, float* __restrict__ pt)
{
    const int row = blockIdx.x;
    const int t = threadIdx.x;
    float4 v = ((const float4*)(y + (size_t)row * HN))[t];
    float s  = v.x + v.y + v.z + v.w;
    float s2 = v.x * v.x + v.y * v.y + v.z * v.z + v.w * v.w;
    #pragma unroll
    for (int off = 32; off > 0; off >>= 1) {
        s  += __shfl_down(s, off);
        s2 += __shfl_down(s2, off);
    }
    __shared__ float ws1[4], ws2[4];
    __shared__ float smu, sinv;
    if ((t & 63) == 0) { ws1[t >> 6] = s; ws2[t >> 6] = s2; }
    __syncthreads();
    if (t == 0) {
        float ts  = ws1[0] + ws1[1] + ws1[2] + ws1[3];
        float ts2 = ws2[0] + ws2[1] + ws2[2] + ws2[3];
        float mu  = ts * (1.0f / 1024.0f);
        float var = ts2 * (1.0f / 1024.0f) - mu * mu;
        smu  = mu;
        sinv = 1.0f / sqrtf(var + 1e-12f);
    }
    __syncthreads();
    const float mu = smu, inv = sinv;
    float4 g = ((const float4*)gamma)[t];
    float4 be = ((const float4*)beta)[t];
    float4 o;
    o.x = (v.x - mu) * inv * g.x + be.x;
    o.y = (v.y - mu) * inv * g.y + be.y;
    o.z = (v.z - mu) * inv * g.z + be.z;
    o.w = (v.w - mu) * inv * g.w + be.w;
    ((float4*)(out + (size_t)row * HN))[t] = o;

    const int b = row >> 10, n = row & 1023;
    const int base = 6 * conv_len[b];
    if (n == base + 3) ((float4*)(he + (size_t)b * HN))[t] = o;
    if (n == base + 2) ((float4*)(pt + (size_t)b * HN))[t] = o;
}

extern "C" void kernel_launch(void* const* d_in, const int* in_sizes, int n_in,
                              void* d_out, int out_size, void* d_ws, size_t ws_size,
                              hipStream_t stream)
{
    const float* hs    = (const float*)d_in[0];
    const int*   mask  = (const int*)d_in[1];
    const int*   clen  = (const int*)d_in[2];
    const float* Wq    = (const float*)d_in[3];
    const float* bq    = (const float*)d_in[4];
    const float* Wk    = (const float*)d_in[5];
    const float* bk    = (const float*)d_in[6];
    const float* Wv    = (const float*)d_in[7];
    const float* bv    = (const float*)d_in[8];
    const float* Wo    = (const float*)d_in[9];
    const float* bo    = (const float*)d_in[10];
    const float* gamma = (const float*)d_in[11];
    const float* beta  = (const float*)d_in[12];
    float* out = (float*)d_out;

    // ws: Ab 16M | Wt3 6M | Wot 2M | Qb 16M | Kb 16M | Vtb 16M | Ctx 16M = 88 MB
    // Yb (fp32, 32M) aliases Qb+Kb (dead after attention).
    unsigned short* Ab  = (unsigned short*)d_ws;
    unsigned short* Wt3 = Ab  + (size_t)M_ROWS * HN;
    unsigned short* Wot = Wt3 + (size_t)3 * HN * HN;
    unsigned short* Qb  = Wot + (size_t)HN * HN;
    unsigned short* Kb  = Qb  + (size_t)M_ROWS * HN;
    unsigned short* Vtb = Kb  + (size_t)M_ROWS * HN;
    unsigned short* Ctx = Vtb + (size_t)M_ROWS * HN;
    float*          Yb  = (float*)Qb;

    dim3 gb(256);

    hipLaunchKernelGGL(cvt_hs_k, dim3((size_t)M_ROWS * HN / 1024), gb, 0, stream, hs, Ab);
    hipLaunchKernelGGL(cvt_wT4_k, dim3(32, 32, 4), gb, 0, stream,
                       Wq, Wk, Wv, Wo,
                       Wt3, Wt3 + (size_t)HN * HN, Wt3 + (size_t)2 * HN * HN, Wot);

    // row-band in x (64 bands): co-XCD blocks share A row-tiles in L2
    hipLaunchKernelGGL(mfma_gemm_k, dim3(64, 24), gb, 0, stream,
                       Ab, Wt3, bq, bk, bv, (const float*)nullptr,
                       Qb, Kb, Vtb, (float*)nullptr, 0);

    // batch in x: XCD = b -> mask/K/V L2-resident per XCD
    hipLaunchKernelGGL(attn_mfma_k, dim3(BB, NN / 128, NHEADS), gb, 0, stream,
                       Qb, Kb, Vtb, mask, Ctx);

    hipLaunchKernelGGL(mfma_gemm_k, dim3(64, 8), gb, 0, stream,
                       Ctx, Wot, bo, (const float*)nullptr, (const float*)nullptr, hs,
                       (unsigned short*)nullptr, (unsigned short*)nullptr,
                       (unsigned short*)nullptr, Yb, 1);

    float* he = out + (size_t)BB * NN * HN;
    float* pt = he + BB * HN;
    hipLaunchKernelGGL(ln_ext_k, dim3(M_ROWS), gb, 0, stream, Yb, gamma, beta, clen,
                       out, he, pt);
}